// Round 1
// baseline (282.051 us; speedup 1.0000x reference)
//
#include <hip/hip_runtime.h>

#define D 64

// One wave (64 lanes) per edge; lane = feature dim.
// N_h[dst[e]][lane] += embed[src[e]][lane] * out_deg[src[e]] * w[e]
__global__ __launch_bounds__(256) void edge_scatter_kernel(
    const float* __restrict__ embed, const int* __restrict__ src,
    const int* __restrict__ dst, const float* __restrict__ ew,
    const float* __restrict__ out_deg, float* __restrict__ Nh, int E)
{
    const int lane = threadIdx.x & 63;
    const int e = blockIdx.x * 4 + (threadIdx.x >> 6);
    if (e >= E) return;
    const int s = src[e];          // wave-uniform -> s_load
    const int d = dst[e];
    const float w = ew[e] * out_deg[s];
    const float v = embed[s * D + lane] * w;
    unsafeAtomicAdd(&Nh[d * D + lane], v);   // native global_atomic_add_f32
}

// out = leaky_relu((embed + Nh * in_deg) @ W^T + b), 64-row tile per block.
__global__ __launch_bounds__(256) void fused_out_kernel(
    const float* __restrict__ embed, const float* __restrict__ Nh,
    const float* __restrict__ in_deg, const float* __restrict__ W,
    const float* __restrict__ b, float* __restrict__ out, int N)
{
    __shared__ float Wt[64 * 65];   // Wt[k*65+c] = W[c][k]; pad 65 -> conflict-free reads
    __shared__ float X[64 * 65];    // X[r*65+k] = embed + Nh*in_deg for 64 rows

    const int t = threadIdx.x;
    for (int idx = t; idx < 4096; idx += 256) {
        const int c = idx >> 6, k = idx & 63;
        Wt[k * 65 + c] = W[idx];
    }
    const int n0 = blockIdx.x * 64;
    for (int idx = t; idx < 4096; idx += 256) {
        const int r = idx >> 6, k = idx & 63;
        const int row = n0 + r;
        float x = 0.f;
        if (row < N) x = embed[row * D + k] + Nh[row * D + k] * in_deg[row];
        X[r * 65 + k] = x;
    }
    __syncthreads();

    const int rg = t >> 6;          // wave id: rows [rg*16, rg*16+16)
    const int c  = t & 63;          // output column
    float acc[16];
    #pragma unroll
    for (int i = 0; i < 16; ++i) acc[i] = 0.f;

    #pragma unroll 4
    for (int k = 0; k < 64; ++k) {
        const float wk = Wt[k * 65 + c];            // lanes consecutive -> no conflict
        #pragma unroll
        for (int i = 0; i < 16; ++i)
            acc[i] += X[(rg * 16 + i) * 65 + k] * wk;  // same-addr broadcast, free
    }

    const float bc = b[c];
    #pragma unroll
    for (int i = 0; i < 16; ++i) {
        const int row = n0 + rg * 16 + i;
        if (row < N) {
            const float v = acc[i] + bc;
            out[row * D + c] = v > 0.f ? v : 0.01f * v;
        }
    }
}

extern "C" void kernel_launch(void* const* d_in, const int* in_sizes, int n_in,
                              void* d_out, int out_size, void* d_ws, size_t ws_size,
                              hipStream_t stream) {
    const float* embed = (const float*)d_in[0];
    const int*   src   = (const int*)  d_in[1];
    const int*   dst   = (const int*)  d_in[2];
    const float* ew    = (const float*)d_in[3];
    const float* odeg  = (const float*)d_in[4];
    const float* ideg  = (const float*)d_in[5];
    const float* W     = (const float*)d_in[6];
    const float* b     = (const float*)d_in[7];
    float* out = (float*)d_out;

    const int N = in_sizes[0] / D;   // 50000
    const int E = in_sizes[1];       // 800000

    float* Nh = (float*)d_ws;        // N*D fp32 accumulator (12.8 MB)
    hipMemsetAsync(Nh, 0, (size_t)N * D * sizeof(float), stream);

    edge_scatter_kernel<<<(E + 3) / 4, 256, 0, stream>>>(embed, src, dst, ew, odeg, Nh, E);
    fused_out_kernel<<<(N + 63) / 64, 256, 0, stream>>>(embed, Nh, ideg, W, b, out, N);
}